// Round 4
// baseline (130.663 us; speedup 1.0000x reference)
//
#include <hip/hip_runtime.h>
#include <math.h>

// Problem constants (from reference): B=1, C=16, H=72, W=96, N=6912
#define NPIX 6912
#define IMW  96
#define NJC  64                 // j-chunks in grid.y
#define JLEN (NPIX / NJC)       // 108 j-iterations per thread

// d_ws float-offset layout (~1.16 MB total)
#define OFF_PACK1 0                         // [N][4]: x0,x1,x2,sq1
#define OFF_PACK2 (OFF_PACK1 + NPIX * 4)    // [N][8]: y0,y1,y2,sq2, z0,z1,z2,sq2n
#define OFF_F1N   (OFF_PACK2 + NPIX * 8)    // [N][16] normalized feature1
#define OFF_F2N   (OFF_F1N + NPIX * 16)     // [N][16] normalized feature2

#if __has_builtin(__builtin_amdgcn_exp2f)
#define EXP2F(x) __builtin_amdgcn_exp2f(x)
#else
#define EXP2F(x) exp2f(x)
#endif
#if __has_builtin(__builtin_amdgcn_sqrtf)
#define SQRTF(x) __builtin_amdgcn_sqrtf(x)
#else
#define SQRTF(x) sqrtf(x)
#endif
// -0.1 * log2(e): folds dist_coef and the exp->exp2 conversion into one mul
#define NEG_COEF_LOG2E (-0.14426950408889634f)

__device__ __forceinline__ float blk_reduce256(float v) {
  __shared__ float sm[4];
#pragma unroll
  for (int o = 32; o > 0; o >>= 1) v += __shfl_down(v, o, 64);
  const int lane = threadIdx.x & 63;
  const int wv = threadIdx.x >> 6;
  if (lane == 0) sm[wv] = v;
  __syncthreads();
  return (sm[0] + sm[1]) + (sm[2] + sm[3]);
}

// Per-pixel precompute: xyz1/sq1, pose-transformed xyz2 (clean+noisy)/sq,
// L2-normalized features (transposed to [N][16]), and the feature-norm sum.
// Pose and pose@noise are computed redundantly per block in LDS (cheap).
__global__ __launch_bounds__(256) void k_pre(
    const float* __restrict__ f1, const float* __restrict__ f2,
    const float* __restrict__ dep1, const float* __restrict__ dep2,
    const float* __restrict__ pose, const float* __restrict__ noise,
    float* __restrict__ ws, float* __restrict__ out) {
  __shared__ float sPose[24];          // [0..11] = P rows0..2, [12..23] = P@noise rows0..2
  const int t = threadIdx.x;
  if (t < 12) {
    sPose[t] = pose[t];
  } else if (t < 24) {
    const int u = t - 12, r = u >> 2, c = u & 3;
    float s = 0.f;
#pragma unroll
    for (int k = 0; k < 4; ++k) s = fmaf(pose[r * 4 + k], noise[k * 4 + c], s);
    sPose[t] = s;
  }
  __syncthreads();

  const int i = blockIdx.x * 256 + t;
  const int vi = i / IMW;
  const int ui = i - vi * IMW;
  // invK @ (u,v,1): p = (1, u/48 - 1, v/48 - 0.75)
  const float inv48 = (float)(1.0 / 48.0);
  const float p1c = fmaf((float)ui, inv48, -1.0f);
  const float p2c = fmaf((float)vi, inv48, -0.75f);

  const float d1 = dep1[i];
  const float x0 = d1, x1 = d1 * p1c, x2 = d1 * p2c;
  const float sq1 = fmaf(x2, x2, fmaf(x1, x1, x0 * x0));
  *(float4*)(ws + OFF_PACK1 + (size_t)i * 4) = make_float4(x0, x1, x2, sq1);

  const float d2 = dep2[i];
  const float w0 = d2, w1 = d2 * p1c, w2 = d2 * p2c;
  const float* P  = sPose;
  const float* Pn = sPose + 12;
  const float y0 = fmaf(P[0], w0, fmaf(P[1], w1, fmaf(P[2],  w2, P[3])));
  const float y1 = fmaf(P[4], w0, fmaf(P[5], w1, fmaf(P[6],  w2, P[7])));
  const float y2 = fmaf(P[8], w0, fmaf(P[9], w1, fmaf(P[10], w2, P[11])));
  const float sq2 = fmaf(y2, y2, fmaf(y1, y1, y0 * y0));
  const float z0 = fmaf(Pn[0], w0, fmaf(Pn[1], w1, fmaf(Pn[2],  w2, Pn[3])));
  const float z1 = fmaf(Pn[4], w0, fmaf(Pn[5], w1, fmaf(Pn[6],  w2, Pn[7])));
  const float z2 = fmaf(Pn[8], w0, fmaf(Pn[9], w1, fmaf(Pn[10], w2, Pn[11])));
  const float sq2n = fmaf(z2, z2, fmaf(z1, z1, z0 * z0));
  *(float4*)(ws + OFF_PACK2 + (size_t)i * 8)     = make_float4(y0, y1, y2, sq2);
  *(float4*)(ws + OFF_PACK2 + (size_t)i * 8 + 4) = make_float4(z0, z1, z2, sq2n);

  float a[16], b[16];
  float sa = 0.f, sb = 0.f;
#pragma unroll
  for (int c = 0; c < 16; ++c) {
    a[c] = f1[c * NPIX + i]; sa = fmaf(a[c], a[c], sa);
    b[c] = f2[c * NPIX + i]; sb = fmaf(b[c], b[c], sb);
  }
  const float na = sqrtf(sa), nb = sqrtf(sb);
#pragma unroll
  for (int c = 0; c < 16; ++c) { a[c] = a[c] / na; b[c] = b[c] / nb; }
#pragma unroll
  for (int c = 0; c < 16; c += 4) {
    *(float4*)(ws + OFF_F1N + (size_t)i * 16 + c) = make_float4(a[c], a[c+1], a[c+2], a[c+3]);
    *(float4*)(ws + OFF_F2N + (size_t)i * 16 + c) = make_float4(b[c], b[c+1], b[c+2], b[c+3]);
  }
  const float part = blk_reduce256(na + nb);
  if (t == 0) atomicAdd(out + 2, 100.0f * part);
}

// Main N x N reduction. Thread owns row i; block stages its j-chunk (10.4 KB)
// into LDS once, then all lanes read uniform addresses (free broadcast, zero
// bank conflicts). Per pair: 16-FMA gram dot + two exp2(c*sqrt(d2)) kernels.
__global__ __launch_bounds__(256) void k_main(const float* __restrict__ ws,
                                              float* __restrict__ out) {
  __shared__ float4 sF[JLEN * 4];   // normalized feature2 chunk
  __shared__ float4 sP[JLEN * 2];   // pack2 chunk (clean + noisy xyz/sq)

  const int j0 = blockIdx.y * JLEN;
  const float4* gF = (const float4*)(ws + OFF_F2N)   + (size_t)j0 * 4;
  const float4* gP = (const float4*)(ws + OFF_PACK2) + (size_t)j0 * 2;
  for (int tt = threadIdx.x; tt < JLEN * 4; tt += 256) sF[tt] = gF[tt];
  for (int tt = threadIdx.x; tt < JLEN * 2; tt += 256) sP[tt] = gP[tt];

  const int i = blockIdx.x * 256 + threadIdx.x;
  const float4 pk = *(const float4*)(ws + OFF_PACK1 + (size_t)i * 4);
  const float x0 = pk.x, x1 = pk.y, x2 = pk.z, sq1 = pk.w;
  float f1r[16];
#pragma unroll
  for (int c = 0; c < 16; c += 4) {
    const float4 tq = *(const float4*)(ws + OFF_F1N + (size_t)i * 16 + c);
    f1r[c] = tq.x; f1r[c+1] = tq.y; f1r[c+2] = tq.z; f1r[c+3] = tq.w;
  }
  __syncthreads();

  // Two independent accumulators (even/odd jj) so the accumulate FMA never
  // serializes on its own 4-cycle latency.
  float acc0 = 0.f, acc1 = 0.f;
#pragma unroll 2
  for (int jj = 0; jj < JLEN; ++jj) {
    const float4 fa = sF[jj * 4 + 0];
    const float4 fb = sF[jj * 4 + 1];
    const float4 fc = sF[jj * 4 + 2];
    const float4 fd = sF[jj * 4 + 3];
    const float4 q  = sP[jj * 2 + 0];
    const float4 r  = sP[jj * 2 + 1];

    // gram dot: 4 independent FMA chains
    float g0 = fmaf(f1r[12], fd.x, fmaf(f1r[8],  fc.x, fmaf(f1r[4], fb.x, f1r[0] * fa.x)));
    float g1 = fmaf(f1r[13], fd.y, fmaf(f1r[9],  fc.y, fmaf(f1r[5], fb.y, f1r[1] * fa.y)));
    float g2 = fmaf(f1r[14], fd.z, fmaf(f1r[10], fc.z, fmaf(f1r[6], fb.z, f1r[2] * fa.z)));
    float g3 = fmaf(f1r[15], fd.w, fmaf(f1r[11], fc.w, fmaf(f1r[7], fb.w, f1r[3] * fa.w)));
    const float g = (g0 + g1) + (g2 + g3);

    // clean kernel: exp(-0.1*sqrt(d2)) == exp2(NEG_COEF_LOG2E * sqrt(d2))
    const float dt = fmaf(x2, q.z, fmaf(x1, q.y, x0 * q.x));
    float d2 = fmaf(-2.f, dt, sq1 + q.w);
    d2 = fmaxf(d2, 0.f);
    const float k1 = EXP2F(NEG_COEF_LOG2E * SQRTF(d2));
    // noisy kernel
    const float dtn = fmaf(x2, r.z, fmaf(x1, r.y, x0 * r.x));
    float d2n = fmaf(-2.f, dtn, sq1 + r.w);
    d2n = fmaxf(d2n, 0.f);
    const float k2 = EXP2F(NEG_COEF_LOG2E * SQRTF(d2n));

    if (jj & 1) acc1 = fmaf(k1 - k2, g, acc1);
    else        acc0 = fmaf(k1 - k2, g, acc0);
  }
  const float part = blk_reduce256(acc0 + acc1);
  if (threadIdx.x == 0) {
    atomicAdd(out + 0, -part);   // final_loss
    atomicAdd(out + 1, -part);   // inner_neg
  }
}

extern "C" void kernel_launch(void* const* d_in, const int* in_sizes, int n_in,
                              void* d_out, int out_size, void* d_ws, size_t ws_size,
                              hipStream_t stream) {
  const float* f1    = (const float*)d_in[0];
  const float* f2    = (const float*)d_in[1];
  const float* dep1  = (const float*)d_in[2];
  const float* dep2  = (const float*)d_in[3];
  const float* pose  = (const float*)d_in[4];
  const float* noise = (const float*)d_in[5];
  float* out = (float*)d_out;
  float* ws  = (float*)d_ws;

  hipMemsetAsync(out, 0, (size_t)out_size * sizeof(float), stream);
  k_pre<<<NPIX / 256, 256, 0, stream>>>(f1, f2, dep1, dep2, pose, noise, ws, out);
  k_main<<<dim3(NPIX / 256, NJC), 256, 0, stream>>>(ws, out);
}